// Round 17
// baseline (292.110 us; speedup 1.0000x reference)
//
#include <hip/hip_runtime.h>
#include <hip/hip_bf16.h>
#include <cstdint>

// ---------- types ----------
typedef __attribute__((ext_vector_type(8))) __bf16 bf16x8;
typedef __attribute__((ext_vector_type(4))) float f32x4;
typedef __attribute__((ext_vector_type(8))) unsigned short u16x8;
typedef __attribute__((ext_vector_type(4))) unsigned short u16x4;

static __device__ __forceinline__ unsigned short f2b(float f) {
    union { float f; unsigned u; } v; v.f = f;
    unsigned r = v.u + 0x7fffu + ((v.u >> 16) & 1u);   // RNE bf16
    return (unsigned short)(r >> 16);
}

// offset field MUST be 0 on gfx950 (nonzero imm corrupted LDS dest -> R3 NaN).
#define LL16(g, l) __builtin_amdgcn_global_load_lds( \
    (const __attribute__((address_space(1))) void*)(g), \
    (__attribute__((address_space(3))) void*)(l), 16, 0, 0)

#define BAR() __builtin_amdgcn_s_barrier()
#define WAIT_VM8() asm volatile("s_waitcnt vmcnt(8)" ::: "memory")
#define WAIT_VM0() asm volatile("s_waitcnt vmcnt(0)" ::: "memory")

// ---------- weight prep: y=0 Wq->bf16, y=1 Wk->bf16, y=2 Wv transpose ----------
__global__ void prep_w(const float* __restrict__ Wq,
                       const float* __restrict__ Wk,
                       const float* __restrict__ Wv,
                       unsigned short* __restrict__ Wqkb,   // [2][1024][1024]
                       unsigned short* __restrict__ Wvt) {  // [1024 n][1024 c]
    __shared__ float tile[32][33];
    const int y = blockIdx.y;
    if (y < 2) {
        long i = (long)blockIdx.x * 256 + threadIdx.x;      // 262144 = 1M/4
        const float* in = y ? Wk : Wq;
        unsigned short* o = Wqkb + (long)y * 1048576;
        float4 a = ((const float4*)in)[i];
        u16x4 r;
        r[0] = f2b(a.x); r[1] = f2b(a.y); r[2] = f2b(a.z); r[3] = f2b(a.w);
        *(u16x4*)(o + i * 4) = r;
        return;
    }
    // transpose Wv [c][n] -> [n][c]
    int n0 = (blockIdx.x & 31) * 32, c0 = (blockIdx.x >> 5) * 32;
    int tx = threadIdx.x & 31, ty = threadIdx.x >> 5;       // 32 x 8
    #pragma unroll
    for (int i = 0; i < 32; i += 8)
        tile[ty + i][tx] = Wv[(long)(c0 + ty + i) * 1024 + n0 + tx];
    __syncthreads();
    #pragma unroll
    for (int i = 0; i < 32; i += 8)
        Wvt[(long)(n0 + ty + i) * 1024 + c0 + tx] = f2b(tile[tx][ty + i]);
}

// ---------- X conversion + u,v row-dots: ONE WAVE PER ROW (no atomics) ----------
__global__ void conv_x(const float* __restrict__ in,
                       unsigned short* __restrict__ out,
                       const float* __restrict__ wqbk,
                       const float* __restrict__ wkbq,
                       float* __restrict__ u, float* __restrict__ v) {
    const long row = (long)blockIdx.x * 4 + (threadIdx.x >> 6);   // 4 waves/block
    const int lane = threadIdx.x & 63;
    const long base = row * 1024 + lane * 16;                     // 16 elems/lane
    const float4* p = (const float4*)(in + base);
    float4 a = p[0], b = p[1], c = p[2], d = p[3];
    u16x8 r0, r1;
    r0[0] = f2b(a.x); r0[1] = f2b(a.y); r0[2] = f2b(a.z); r0[3] = f2b(a.w);
    r0[4] = f2b(b.x); r0[5] = f2b(b.y); r0[6] = f2b(b.z); r0[7] = f2b(b.w);
    r1[0] = f2b(c.x); r1[1] = f2b(c.y); r1[2] = f2b(c.z); r1[3] = f2b(c.w);
    r1[4] = f2b(d.x); r1[5] = f2b(d.y); r1[6] = f2b(d.z); r1[7] = f2b(d.w);
    *(u16x8*)(out + base) = r0;
    *(u16x8*)(out + base + 8) = r1;
    const float4* wq = (const float4*)(wqbk + lane * 16);
    const float4* wk = (const float4*)(wkbq + lane * 16);
    float4 q0 = wq[0], q1 = wq[1], q2 = wq[2], q3 = wq[3];
    float4 k0 = wk[0], k1 = wk[1], k2 = wk[2], k3 = wk[3];
    float du = a.x*q0.x + a.y*q0.y + a.z*q0.z + a.w*q0.w
             + b.x*q1.x + b.y*q1.y + b.z*q1.z + b.w*q1.w
             + c.x*q2.x + c.y*q2.y + c.z*q2.z + c.w*q2.w
             + d.x*q3.x + d.y*q3.y + d.z*q3.z + d.w*q3.w;
    float dv = a.x*k0.x + a.y*k0.y + a.z*k0.z + a.w*k0.w
             + b.x*k1.x + b.y*k1.y + b.z*k1.z + b.w*k1.w
             + c.x*k2.x + c.y*k2.y + c.z*k2.z + c.w*k2.w
             + d.x*k3.x + d.y*k3.y + d.z*k3.z + d.w*k3.w;
    #pragma unroll
    for (int s = 1; s < 64; s <<= 1) {
        du += __shfl_xor(du, s);
        dv += __shfl_xor(dv, s);
    }
    if (lane == 0) { u[row] = du; v[row] = dv; }
}

// ---------- wqbk = Wq.bk, wkbq = Wk.bq (one wave per c), cbuf = bq.bk ----------
__global__ void wdots(const float* __restrict__ Wq, const float* __restrict__ bq,
                      const float* __restrict__ Wk, const float* __restrict__ bk,
                      float* __restrict__ wqbk, float* __restrict__ wkbq,
                      float* __restrict__ cbuf) {
    const int lane = threadIdx.x & 63;
    if (blockIdx.x == 256) {
        float s = 0.f;
        for (int k = threadIdx.x; k < 1024; k += 256) s += bq[k] * bk[k];
        #pragma unroll
        for (int sh = 1; sh < 64; sh <<= 1) s += __shfl_xor(s, sh);
        __shared__ float ps[4];
        if (lane == 0) ps[threadIdx.x >> 6] = s;
        __syncthreads();
        if (threadIdx.x == 0) cbuf[0] = ps[0] + ps[1] + ps[2] + ps[3];
        return;
    }
    const int c = blockIdx.x * 4 + (threadIdx.x >> 6);
    const float* wq = Wq + (long)c * 1024;
    const float* wk = Wk + (long)c * 1024;
    float sq = 0.f, sk = 0.f;
    for (int k0 = 0; k0 < 1024; k0 += 256) {
        int k = k0 + lane * 4;
        float4 q4 = *(const float4*)(wq + k);
        float4 k4 = *(const float4*)(wk + k);
        float4 b4 = *(const float4*)(bk + k);
        float4 a4 = *(const float4*)(bq + k);
        sq += q4.x*b4.x + q4.y*b4.y + q4.z*b4.z + q4.w*b4.w;
        sk += k4.x*a4.x + k4.y*a4.y + k4.z*a4.z + k4.w*a4.w;
    }
    #pragma unroll
    for (int sh = 1; sh < 64; sh <<= 1) {
        sq += __shfl_xor(sq, sh);
        sk += __shfl_xor(sk, sh);
    }
    if (lane == 0) { wqbk[c] = sq; wkbq[c] = sk; }
}

// =====================================================================
// 128x128 tile, BK=64, 4 waves (2x2, 64x64/wave), 64 KiB double-
// buffered LDS, 2 blocks/CU  [MEASURED BEST of the session ladder:
// {1blk any sched}=26% MfmaUtil; {2blk dbuf counted}=30% (this);
// {3blk sbuf drain}=24.6%; {4blk dbuf BK32}=25.5% + 9.4M conflicts
// (64B LDS rows give only 1 bank-bit per row -> 16-row b128 reads are
// structurally 8-way); 32x32 frags = 4-way; tighter bounds = spill].
// 16 b128-reads per 32 MFMA is the info-theoretic minimum for 64x64
// wave tiles -- this structure is at its family optimum.
// Loop: {vmcnt(8) pre-satisfied; BAR; 16 ds_read_b128 + 32 MFMA; BAR;
// STAGE(t+2)}. Swizzle chunk^=(row&7) on stage-source AND read.
// Supertile-4 block order for L2.
// MODE 0: plain bf16                      (Y = X.Zt, Z = Wk.Wq^T)
// MODE 1: (+bias[row]) / colsum[t], bf16  (V^T proj, scale_vt fused)
// MODE 2: exp((s+u[q]+v[t]+c)/32), bf16 + atomic colsum  (scores)
// MODE 3: * mask[row], f32                (PV -> output)
// =====================================================================

template<int MODE>
__global__ __launch_bounds__(256, 2)
void gemm128(const unsigned short* __restrict__ Aall,
             const unsigned short* __restrict__ Ball,
             void* __restrict__ Cv,
             int M, int N, int K, int ldc,
             long aStride, long bStride, long cStride,
             const float* __restrict__ aux, float* __restrict__ colsum) {
    __shared__ unsigned short lds[32768];        // 64 KiB

    // XCD swizzle + bx-minor supertiles of 4 (gx % 4 == 0, nwg % 8 == 0)
    const int gx = gridDim.x, gy = gridDim.y;
    const int nxy = gx * gy;
    const int nwg = nxy * gridDim.z;
    const int orig = (blockIdx.z * gy + blockIdx.y) * gx + blockIdx.x;
    const int swz = (orig & 7) * (nwg >> 3) + (orig >> 3);
    const int bz = swz / nxy;
    const int rem = swz - bz * nxy;
    const int sb = rem / (gy * 4);
    const int r2 = rem - sb * (gy * 4);
    const int by = r2 >> 2;
    const int bx = sb * 4 + (r2 & 3);

    const unsigned short* A  = Aall + (long)bz * aStride;
    const unsigned short* Bt = Ball + (long)bz * bStride;

    const int tid = threadIdx.x;
    const int lane = tid & 63;
    const int w = tid >> 6;                  // 0..3
    const int wrow = w >> 1, wcol = w & 1;   // 2 x 2 wave grid
    const int lr = lane & 15, lg = lane >> 4;

    const int bm = by * 128, bn = bx * 128;
    const int NT = K >> 6;

    const int r0 = tid >> 3;                 // 0..31
    const int c0 = (tid & 7) ^ (r0 & 7);
    const unsigned short* sA0 = A  + (long)(bm + r0)      * K + c0 * 8;
    const unsigned short* sA1 = A  + (long)(bm + 32 + r0) * K + c0 * 8;
    const unsigned short* sA2 = A  + (long)(bm + 64 + r0) * K + c0 * 8;
    const unsigned short* sA3 = A  + (long)(bm + 96 + r0) * K + c0 * 8;
    const unsigned short* sB0 = Bt + (long)(bn + r0)      * K + c0 * 8;
    const unsigned short* sB1 = Bt + (long)(bn + 32 + r0) * K + c0 * 8;
    const unsigned short* sB2 = Bt + (long)(bn + 64 + r0) * K + c0 * 8;
    const unsigned short* sB3 = Bt + (long)(bn + 96 + r0) * K + c0 * 8;
    const int dstT = tid * 8;

    const int cx0 = (lg ^ (lr & 7)) * 8;
    const int cx1 = ((4 + lg) ^ (lr & 7)) * 8;
    const int baA = (wrow * 64 + lr) * 64;
    const int baB = 16384 + (wcol * 64 + lr) * 64;

    bf16x8 af[4][2], bf[4][2];
    f32x4 acc[4][4] = {};

    #define STAGE(kt, buf) do { const long ko = (long)(kt) * 64; \
        LL16(sA0 + ko, lds + (buf) * 8192 + dstT); \
        LL16(sA1 + ko, lds + (buf) * 8192 + 2048 + dstT); \
        LL16(sA2 + ko, lds + (buf) * 8192 + 4096 + dstT); \
        LL16(sA3 + ko, lds + (buf) * 8192 + 6144 + dstT); \
        LL16(sB0 + ko, lds + 16384 + (buf) * 8192 + dstT); \
        LL16(sB1 + ko, lds + 16384 + (buf) * 8192 + 2048 + dstT); \
        LL16(sB2 + ko, lds + 16384 + (buf) * 8192 + 4096 + dstT); \
        LL16(sB3 + ko, lds + 16384 + (buf) * 8192 + 6144 + dstT); } while (0)

    // prologue: tiles 0,1 in flight (16 vm ops)
    STAGE(0, 0);
    STAGE(1, 1);

    for (int t = 0; t < NT; ++t) {
        if (t < NT - 1) { WAIT_VM8(); } else { WAIT_VM0(); }  // tile t landed
        BAR();                                                // block-wide visible

        const int aB = (t & 1) * 8192;
        const int bB = (t & 1) * 8192;
        #pragma unroll
        for (int mi = 0; mi < 4; ++mi) {
            af[mi][0] = *(const bf16x8*)(lds + aB + baA + mi * 1024 + cx0);
            af[mi][1] = *(const bf16x8*)(lds + aB + baA + mi * 1024 + cx1);
        }
        #pragma unroll
        for (int nj = 0; nj < 4; ++nj) {
            bf[nj][0] = *(const bf16x8*)(lds + bB + baB + nj * 1024 + cx0);
            bf[nj][1] = *(const bf16x8*)(lds + bB + baB + nj * 1024 + cx1);
        }
        __builtin_amdgcn_s_setprio(1);
        #pragma unroll
        for (int mi = 0; mi < 4; ++mi)
            #pragma unroll
            for (int nj = 0; nj < 4; ++nj) {
                acc[mi][nj] = __builtin_amdgcn_mfma_f32_16x16x32_bf16(
                    af[mi][0], bf[nj][0], acc[mi][nj], 0, 0, 0);
                acc[mi][nj] = __builtin_amdgcn_mfma_f32_16x16x32_bf16(
                    af[mi][1], bf[nj][1], acc[mi][nj], 0, 0, 0);
            }
        __builtin_amdgcn_s_setprio(0);

        BAR();                                // reads done before next overwrite
        if (t + 2 < NT) STAGE(t + 2, t & 1);  // overwrite just-freed buffer
    }
    #undef STAGE

    // ---- epilogue: repack through LDS for coalesced stores ----
    if (MODE != 3) {
        unsigned short* C = (unsigned short*)Cv + (long)bz * cStride;
        float* cs = colsum + (long)bz * 2048;
        const float cQK = (MODE == 2) ? aux[32768] : 0.f;
        #pragma unroll
        for (int nj = 0; nj < 4; ++nj) {
            const int cl = wcol * 64 + nj * 16 + lr;
            const int cb = cl >> 3, cIn = cl & 7;
            float vcol = (MODE == 2) ? (aux[16384 + bz * 2048 + bn + cl] + cQK) : 0.f;
            const float inv = (MODE == 1) ? 1.0f / cs[bn + cl] : 1.f;  // fused scale_vt
            float psum = 0.f;
            #pragma unroll
            for (int mi = 0; mi < 4; ++mi) {
                #pragma unroll
                for (int r = 0; r < 4; ++r) {
                    const int rl = wrow * 64 + mi * 16 + lg * 4 + r;
                    float val = acc[mi][nj][r];
                    if (MODE == 1) val = (val + aux[bm + rl]) * inv;
                    else if (MODE == 2) {
                        val = __expf((val + aux[bz * 2048 + bm + rl] + vcol) * 0.03125f);
                        psum += val;
                    }
                    lds[rl * 128 + ((cb ^ ((rl & 7) << 1)) << 3) + cIn] = f2b(val);
                }
            }
            if (MODE == 2) {
                psum += __shfl_xor(psum, 16);
                psum += __shfl_xor(psum, 32);
                if (lg == 0) atomicAdd(&cs[bn + cl], psum);
            }
        }
        BAR();
        #pragma unroll
        for (int it = 0; it < 8; ++it) {
            int lin = it * 256 + tid;
            int row = lin >> 4;
            int c = lin & 15;
            u16x8 v = *(const u16x8*)&lds[row * 128 + ((c ^ ((row & 7) << 1)) << 3)];
            *(u16x8*)&C[(long)(bm + row) * ldc + bn + c * 8] = v;
        }
    } else {
        float* C = (float*)Cv + (long)bz * cStride;
        const float* mk = aux + (long)bz * 2048;
        float* ft = (float*)lds;
        #pragma unroll
        for (int nj = 0; nj < 4; ++nj) {
            const int cl = wcol * 64 + nj * 16 + lr;
            const int cf = cl >> 2, cIn = cl & 3;
            #pragma unroll
            for (int mi = 0; mi < 4; ++mi) {
                #pragma unroll
                for (int r = 0; r < 4; ++r) {
                    const int rl = wrow * 64 + mi * 16 + lg * 4 + r;
                    ft[rl * 128 + ((cf ^ ((rl & 7) << 2)) << 2) + cIn] =
                        acc[mi][nj][r] * mk[bm + rl];
                }
            }
        }
        BAR();
        #pragma unroll
        for (int it = 0; it < 16; ++it) {
            int lin = it * 256 + tid;
            int row = lin >> 5;
            int cf = lin & 31;
            float4 v = *(const float4*)&ft[row * 128 + ((cf ^ ((row & 7) << 2)) << 2)];
            *(float4*)&C[(long)(bm + row) * ldc + bn + cf * 4] = v;
        }
    }
}

// ---------- host ----------
extern "C" void kernel_launch(void* const* d_in, const int* in_sizes, int n_in,
                              void* d_out, int out_size, void* d_ws, size_t ws_size,
                              hipStream_t stream) {
    const float* x    = (const float*)d_in[0];   // [8,2048,1024]
    const float* mask = (const float*)d_in[1];   // [8,2048,1]
    const float* Wq   = (const float*)d_in[2];
    const float* bq   = (const float*)d_in[3];
    const float* Wk   = (const float*)d_in[4];
    const float* bk   = (const float*)d_in[5];
    const float* Wv   = (const float*)d_in[6];
    const float* bv   = (const float*)d_in[7];
    float* out = (float*)d_out;

    const long MT = 16384;           // B*T
    unsigned short* Xb  = (unsigned short*)d_ws;       // [16384][1024]
    unsigned short* Wqb = Xb + MT * 1024;              // [2][1024][1024] (Wq,Wk bf16)
    unsigned short* Wkb = Wqb + 1048576;
    unsigned short* Wvt = Wkb + 1048576;               // [1024 n][1024 c]
    unsigned short* Y   = Wvt + 1048576;               // [16384][1024]  (= X.Wqk)
    unsigned short* Z   = Y + MT * 1024;               // [1024][1024]   (= Wk.Wq^T)
    unsigned short* Vt  = Z + MT * 1024;               // [8][1024 v][2048 t]
    unsigned short* E   = Vt + 8L * 1024 * 2048;       // [8][2048 q][2048 t]
    float* colsum = (float*)(E + 8L * 2048 * 2048);    // [16384]
    float* u      = colsum + 16384;                    // [16384]
    float* v      = u + 16384;                         // [16384]
    float* cbuf   = v + 16384;
    float* wqbk   = cbuf + 1;                          // [1024]
    float* wkbq   = wqbk + 1024;                       // [1024]
    size_t need = (size_t)((char*)(wkbq + 1024) - (char*)d_ws);
    if (ws_size < need) return;

    // 0. zero colsum only (u,v written directly by conv_x now)
    hipMemsetAsync(colsum, 0, 16384 * sizeof(float), stream);
    // 1. wqbk/wkbq/c
    wdots<<<257, 256, 0, stream>>>(Wq, bq, Wk, bk, wqbk, wkbq, cbuf);
    // 2. X -> bf16, fused u,v row-dots (one wave per row, no atomics)
    conv_x<<<4096, 256, 0, stream>>>(x, Xb, wqbk, wkbq, u, v);
    // 3. weight prep: Wq,Wk convert + Wv transpose in ONE dispatch
    prep_w<<<dim3(1024, 3), 256, 0, stream>>>(Wq, Wk, Wv, Wqb, Wvt);
    // 4. Z = Wk.Wq^T  (so Z[n][k] = Wqk[k][n] = scores B-operand form)
    gemm128<0><<<dim3(8, 8, 1), 256, 0, stream>>>(
        Wkb, Wqb, Z, 1024, 1024, 1024, 1024, 0, 0, 0, nullptr, nullptr);
    // 5. Y = X.Wqk  (A = Xb, Bt = Z)  -- replaces the Q projection
    gemm128<0><<<dim3(8, 128, 1), 256, 0, stream>>>(
        Xb, Z, Y, 16384, 1024, 1024, 1024, 0, 0, 0, nullptr, nullptr);
    // 6. E = exp((Y.X^T + u + v + c)/32) + atomic colsums  (K proj eliminated)
    gemm128<2><<<dim3(16, 16, 8), 256, 0, stream>>>(
        Y, Xb, E, 2048, 2048, 1024, 2048,
        2048L * 1024, 2048L * 1024, 2048L * 2048, u, colsum);
    // 7. Vt[b] = ((X_b Wv + bv)^T) / colsum  -- scale_vt fused into epilogue
    gemm128<1><<<dim3(16, 8, 8), 256, 0, stream>>>(
        Wvt, Xb, Vt, 1024, 2048, 1024, 2048,
        0, 2048L * 1024, 1024L * 2048, bv, colsum);
    // 8. out[b] = E_b @ Vn_b^T * mask
    gemm128<3><<<dim3(8, 16, 8), 256, 0, stream>>>(
        E, Vt, out, 2048, 1024, 2048, 1024,
        2048L * 2048, 1024L * 2048, 2048L * 1024, mask, nullptr);
}

// Round 18
// 287.111 us; speedup vs baseline: 1.0174x; 1.0174x over previous
//
#include <hip/hip_runtime.h>
#include <hip/hip_bf16.h>
#include <cstdint>

// ---------- types ----------
typedef __attribute__((ext_vector_type(8))) __bf16 bf16x8;
typedef __attribute__((ext_vector_type(4))) float f32x4;
typedef __attribute__((ext_vector_type(8))) unsigned short u16x8;

static __device__ __forceinline__ unsigned short f2b(float f) {
    union { float f; unsigned u; } v; v.f = f;
    unsigned r = v.u + 0x7fffu + ((v.u >> 16) & 1u);   // RNE bf16
    return (unsigned short)(r >> 16);
}
static __device__ __forceinline__ float b2f(unsigned short b) {
    union { unsigned u; float f; } v; v.u = ((unsigned)b) << 16;
    return v.f;
}

// offset field MUST be 0 on gfx950 (nonzero imm corrupted LDS dest -> R3 NaN).
#define LL16(g, l) __builtin_amdgcn_global_load_lds( \
    (const __attribute__((address_space(1))) void*)(g), \
    (__attribute__((address_space(3))) void*)(l), 16, 0, 0)

#define BAR() __builtin_amdgcn_s_barrier()
#define WAIT_VM8() asm volatile("s_waitcnt vmcnt(8)" ::: "memory")
#define WAIT_VM0() asm volatile("s_waitcnt vmcnt(0)" ::: "memory")

// ---------- Wq,Wk fp32 -> bf16 (one dispatch, y picks source) ----------
__global__ void conv_w2(const float* __restrict__ w0,
                        const float* __restrict__ w1,
                        unsigned short* __restrict__ out) {
    long i = (long)blockIdx.x * blockDim.x + threadIdx.x;   // 131072 per y
    const float* in = blockIdx.y ? w1 : w0;
    unsigned short* o = out + (long)blockIdx.y * 1048576;
    const float4* p = (const float4*)in + i * 2;
    float4 a = p[0], b = p[1];
    u16x8 r;
    r[0] = f2b(a.x); r[1] = f2b(a.y); r[2] = f2b(a.z); r[3] = f2b(a.w);
    r[4] = f2b(b.x); r[5] = f2b(b.y); r[6] = f2b(b.z); r[7] = f2b(b.w);
    *(u16x8*)(o + i * 8) = r;
}

// ---------- X conversion + u,v row-dots (u=X.wqbk, v=X.wkbq) ----------
__global__ void conv_x(const float* __restrict__ in,
                       unsigned short* __restrict__ out,
                       const float* __restrict__ wqbk,
                       const float* __restrict__ wkbq,
                       float* __restrict__ u, float* __restrict__ v) {
    long i = (long)blockIdx.x * blockDim.x + threadIdx.x;   // 2M threads
    const float4* p = (const float4*)in + i * 2;
    float4 a = p[0], b = p[1];
    u16x8 r;
    r[0] = f2b(a.x); r[1] = f2b(a.y); r[2] = f2b(a.z); r[3] = f2b(a.w);
    r[4] = f2b(b.x); r[5] = f2b(b.y); r[6] = f2b(b.z); r[7] = f2b(b.w);
    *(u16x8*)(out + i * 8) = r;
    const int c = (int)(i & 127) * 8;       // col base within row
    const long row = i >> 7;                // 128 threads per 1024-col row
    const float* wq = wqbk + c;
    const float* wk = wkbq + c;
    float du = a.x*wq[0] + a.y*wq[1] + a.z*wq[2] + a.w*wq[3]
             + b.x*wq[4] + b.y*wq[5] + b.z*wq[6] + b.w*wq[7];
    float dv = a.x*wk[0] + a.y*wk[1] + a.z*wk[2] + a.w*wk[3]
             + b.x*wk[4] + b.y*wk[5] + b.z*wk[6] + b.w*wk[7];
    #pragma unroll
    for (int s = 1; s < 64; s <<= 1) {
        du += __shfl_xor(du, s);
        dv += __shfl_xor(dv, s);
    }
    if ((threadIdx.x & 63) == 0) {          // one wave = half a row
        atomicAdd(&u[row], du);
        atomicAdd(&v[row], dv);
    }
}

// ---------- wqbk = Wq.bk, wkbq = Wk.bq (one wave per c), cbuf = bq.bk ----------
__global__ void wdots(const float* __restrict__ Wq, const float* __restrict__ bq,
                      const float* __restrict__ Wk, const float* __restrict__ bk,
                      float* __restrict__ wqbk, float* __restrict__ wkbq,
                      float* __restrict__ cbuf) {
    const int lane = threadIdx.x & 63;
    if (blockIdx.x == 256) {
        float s = 0.f;
        for (int k = threadIdx.x; k < 1024; k += 256) s += bq[k] * bk[k];
        #pragma unroll
        for (int sh = 1; sh < 64; sh <<= 1) s += __shfl_xor(s, sh);
        __shared__ float ps[4];
        if (lane == 0) ps[threadIdx.x >> 6] = s;
        __syncthreads();
        if (threadIdx.x == 0) cbuf[0] = ps[0] + ps[1] + ps[2] + ps[3];
        return;
    }
    const int c = blockIdx.x * 4 + (threadIdx.x >> 6);
    const float* wq = Wq + (long)c * 1024;
    const float* wk = Wk + (long)c * 1024;
    float sq = 0.f, sk = 0.f;
    for (int k0 = 0; k0 < 1024; k0 += 256) {
        int k = k0 + lane * 4;
        float4 q4 = *(const float4*)(wq + k);
        float4 k4 = *(const float4*)(wk + k);
        float4 b4 = *(const float4*)(bk + k);
        float4 a4 = *(const float4*)(bq + k);
        sq += q4.x*b4.x + q4.y*b4.y + q4.z*b4.z + q4.w*b4.w;
        sk += k4.x*a4.x + k4.y*a4.y + k4.z*a4.z + k4.w*a4.w;
    }
    #pragma unroll
    for (int sh = 1; sh < 64; sh <<= 1) {
        sq += __shfl_xor(sq, sh);
        sk += __shfl_xor(sk, sh);
    }
    if (lane == 0) { wqbk[c] = sq; wkbq[c] = sk; }
}

// ---------- Wv [c][n] f32 -> Wvt [n][c] bf16 ----------
__global__ void transpose_wv(const float* __restrict__ W,
                             unsigned short* __restrict__ out) {
    __shared__ float tile[32][33];
    int n0 = blockIdx.x * 32, c0 = blockIdx.y * 32;
    int tx = threadIdx.x & 31, ty = threadIdx.x >> 5;   // 32 x 8
    #pragma unroll
    for (int i = 0; i < 32; i += 8)
        tile[ty + i][tx] = W[(long)(c0 + ty + i) * 1024 + n0 + tx];
    __syncthreads();
    #pragma unroll
    for (int i = 0; i < 32; i += 8)
        out[(long)(n0 + ty + i) * 1024 + c0 + tx] = f2b(tile[tx][ty + i]);
}

// =====================================================================
// 128x128 tile, BK=64, 4 waves (2x2, 64x64/wave), 64 KiB double-
// buffered LDS, 2 blocks/CU  [MEASURED BEST of the session ladder:
// {1blk any sched}=26% MfmaUtil; {2blk dbuf counted}=30% (this);
// {3blk sbuf drain}=24.6%; {4blk dbuf BK32}=25.5% + 9.4M conflicts
// (64B LDS rows give only 1 bank-bit per row -> 16-row b128 reads are
// structurally 8-way); 32x32 frags = 4-way; tighter bounds = spill].
// 16 b128-reads per 32 MFMA is the info-theoretic minimum for 64x64
// wave tiles -- this structure is at its family optimum.
// Loop: {vmcnt(8) pre-satisfied; BAR; 16 ds_read_b128 + 32 MFMA; BAR;
// STAGE(t+2)}. Swizzle chunk^=(row&7) on stage-source AND read.
// Supertile-4 block order for L2.
// MODE 0: plain bf16                      (Y = X.Zt, Z = Wk.Wq^T)
// MODE 1: (+bias[row]) / colsum[t], bf16  (V^T proj, scale_vt fused)
// MODE 2: exp((s+u[q]+v[t]+c)/32), bf16 + atomic colsum  (scores)
// MODE 3: * mask[row], f32                (PV -> output)
// =====================================================================

template<int MODE>
__global__ __launch_bounds__(256, 2)
void gemm128(const unsigned short* __restrict__ Aall,
             const unsigned short* __restrict__ Ball,
             void* __restrict__ Cv,
             int M, int N, int K, int ldc,
             long aStride, long bStride, long cStride,
             const float* __restrict__ aux, float* __restrict__ colsum) {
    __shared__ unsigned short lds[32768];        // 64 KiB

    // XCD swizzle + bx-minor supertiles of 4 (gx % 4 == 0, nwg % 8 == 0)
    const int gx = gridDim.x, gy = gridDim.y;
    const int nxy = gx * gy;
    const int nwg = nxy * gridDim.z;
    const int orig = (blockIdx.z * gy + blockIdx.y) * gx + blockIdx.x;
    const int swz = (orig & 7) * (nwg >> 3) + (orig >> 3);
    const int bz = swz / nxy;
    const int rem = swz - bz * nxy;
    const int sb = rem / (gy * 4);
    const int r2 = rem - sb * (gy * 4);
    const int by = r2 >> 2;
    const int bx = sb * 4 + (r2 & 3);

    const unsigned short* A  = Aall + (long)bz * aStride;
    const unsigned short* Bt = Ball + (long)bz * bStride;

    const int tid = threadIdx.x;
    const int lane = tid & 63;
    const int w = tid >> 6;                  // 0..3
    const int wrow = w >> 1, wcol = w & 1;   // 2 x 2 wave grid
    const int lr = lane & 15, lg = lane >> 4;

    const int bm = by * 128, bn = bx * 128;
    const int NT = K >> 6;

    const int r0 = tid >> 3;                 // 0..31
    const int c0 = (tid & 7) ^ (r0 & 7);
    const unsigned short* sA0 = A  + (long)(bm + r0)      * K + c0 * 8;
    const unsigned short* sA1 = A  + (long)(bm + 32 + r0) * K + c0 * 8;
    const unsigned short* sA2 = A  + (long)(bm + 64 + r0) * K + c0 * 8;
    const unsigned short* sA3 = A  + (long)(bm + 96 + r0) * K + c0 * 8;
    const unsigned short* sB0 = Bt + (long)(bn + r0)      * K + c0 * 8;
    const unsigned short* sB1 = Bt + (long)(bn + 32 + r0) * K + c0 * 8;
    const unsigned short* sB2 = Bt + (long)(bn + 64 + r0) * K + c0 * 8;
    const unsigned short* sB3 = Bt + (long)(bn + 96 + r0) * K + c0 * 8;
    const int dstT = tid * 8;

    const int cx0 = (lg ^ (lr & 7)) * 8;
    const int cx1 = ((4 + lg) ^ (lr & 7)) * 8;
    const int baA = (wrow * 64 + lr) * 64;
    const int baB = 16384 + (wcol * 64 + lr) * 64;

    bf16x8 af[4][2], bf[4][2];
    f32x4 acc[4][4] = {};

    #define STAGE(kt, buf) do { const long ko = (long)(kt) * 64; \
        LL16(sA0 + ko, lds + (buf) * 8192 + dstT); \
        LL16(sA1 + ko, lds + (buf) * 8192 + 2048 + dstT); \
        LL16(sA2 + ko, lds + (buf) * 8192 + 4096 + dstT); \
        LL16(sA3 + ko, lds + (buf) * 8192 + 6144 + dstT); \
        LL16(sB0 + ko, lds + 16384 + (buf) * 8192 + dstT); \
        LL16(sB1 + ko, lds + 16384 + (buf) * 8192 + 2048 + dstT); \
        LL16(sB2 + ko, lds + 16384 + (buf) * 8192 + 4096 + dstT); \
        LL16(sB3 + ko, lds + 16384 + (buf) * 8192 + 6144 + dstT); } while (0)

    // prologue: tiles 0,1 in flight (16 vm ops)
    STAGE(0, 0);
    STAGE(1, 1);

    for (int t = 0; t < NT; ++t) {
        if (t < NT - 1) { WAIT_VM8(); } else { WAIT_VM0(); }  // tile t landed
        BAR();                                                // block-wide visible

        const int aB = (t & 1) * 8192;
        const int bB = (t & 1) * 8192;
        #pragma unroll
        for (int mi = 0; mi < 4; ++mi) {
            af[mi][0] = *(const bf16x8*)(lds + aB + baA + mi * 1024 + cx0);
            af[mi][1] = *(const bf16x8*)(lds + aB + baA + mi * 1024 + cx1);
        }
        #pragma unroll
        for (int nj = 0; nj < 4; ++nj) {
            bf[nj][0] = *(const bf16x8*)(lds + bB + baB + nj * 1024 + cx0);
            bf[nj][1] = *(const bf16x8*)(lds + bB + baB + nj * 1024 + cx1);
        }
        __builtin_amdgcn_s_setprio(1);
        #pragma unroll
        for (int mi = 0; mi < 4; ++mi)
            #pragma unroll
            for (int nj = 0; nj < 4; ++nj) {
                acc[mi][nj] = __builtin_amdgcn_mfma_f32_16x16x32_bf16(
                    af[mi][0], bf[nj][0], acc[mi][nj], 0, 0, 0);
                acc[mi][nj] = __builtin_amdgcn_mfma_f32_16x16x32_bf16(
                    af[mi][1], bf[nj][1], acc[mi][nj], 0, 0, 0);
            }
        __builtin_amdgcn_s_setprio(0);

        BAR();                                // reads done before next overwrite
        if (t + 2 < NT) STAGE(t + 2, t & 1);  // overwrite just-freed buffer
    }
    #undef STAGE

    // ---- epilogue: repack through LDS for coalesced stores ----
    if (MODE != 3) {
        unsigned short* C = (unsigned short*)Cv + (long)bz * cStride;
        float* cs = colsum + (long)bz * 2048;
        const float cQK = (MODE == 2) ? aux[32768] : 0.f;
        #pragma unroll
        for (int nj = 0; nj < 4; ++nj) {
            const int cl = wcol * 64 + nj * 16 + lr;
            const int cb = cl >> 3, cIn = cl & 7;
            float vcol = (MODE == 2) ? (aux[16384 + bz * 2048 + bn + cl] + cQK) : 0.f;
            const float inv = (MODE == 1) ? 1.0f / cs[bn + cl] : 1.f;  // fused scale_vt
            float psum = 0.f;
            #pragma unroll
            for (int mi = 0; mi < 4; ++mi) {
                #pragma unroll
                for (int r = 0; r < 4; ++r) {
                    const int rl = wrow * 64 + mi * 16 + lg * 4 + r;
                    float val = acc[mi][nj][r];
                    if (MODE == 1) val = (val + aux[bm + rl]) * inv;
                    else if (MODE == 2) {
                        val = __expf((val + aux[bz * 2048 + bm + rl] + vcol) * 0.03125f);
                        psum += val;
                    }
                    lds[rl * 128 + ((cb ^ ((rl & 7) << 1)) << 3) + cIn] = f2b(val);
                }
            }
            if (MODE == 2) {
                psum += __shfl_xor(psum, 16);
                psum += __shfl_xor(psum, 32);
                if (lg == 0) atomicAdd(&cs[bn + cl], psum);
            }
        }
        BAR();
        #pragma unroll
        for (int it = 0; it < 8; ++it) {
            int lin = it * 256 + tid;
            int row = lin >> 4;
            int c = lin & 15;
            u16x8 v = *(const u16x8*)&lds[row * 128 + ((c ^ ((row & 7) << 1)) << 3)];
            *(u16x8*)&C[(long)(bm + row) * ldc + bn + c * 8] = v;
        }
    } else {
        float* C = (float*)Cv + (long)bz * cStride;
        const float* mk = aux + (long)bz * 2048;
        float* ft = (float*)lds;
        #pragma unroll
        for (int nj = 0; nj < 4; ++nj) {
            const int cl = wcol * 64 + nj * 16 + lr;
            const int cf = cl >> 2, cIn = cl & 3;
            #pragma unroll
            for (int mi = 0; mi < 4; ++mi) {
                #pragma unroll
                for (int r = 0; r < 4; ++r) {
                    const int rl = wrow * 64 + mi * 16 + lg * 4 + r;
                    ft[rl * 128 + ((cf ^ ((rl & 7) << 2)) << 2) + cIn] =
                        acc[mi][nj][r] * mk[bm + rl];
                }
            }
        }
        BAR();
        #pragma unroll
        for (int it = 0; it < 16; ++it) {
            int lin = it * 256 + tid;
            int row = lin >> 5;
            int cf = lin & 31;
            float4 v = *(const float4*)&ft[row * 128 + ((cf ^ ((row & 7) << 2)) << 2)];
            *(float4*)&C[(long)(bm + row) * ldc + bn + cf * 4] = v;
        }
    }
}

// ---------- host ----------
extern "C" void kernel_launch(void* const* d_in, const int* in_sizes, int n_in,
                              void* d_out, int out_size, void* d_ws, size_t ws_size,
                              hipStream_t stream) {
    const float* x    = (const float*)d_in[0];   // [8,2048,1024]
    const float* mask = (const float*)d_in[1];   // [8,2048,1]
    const float* Wq   = (const float*)d_in[2];
    const float* bq   = (const float*)d_in[3];
    const float* Wk   = (const float*)d_in[4];
    const float* bk   = (const float*)d_in[5];
    const float* Wv   = (const float*)d_in[6];
    const float* bv   = (const float*)d_in[7];
    float* out = (float*)d_out;

    const long MT = 16384;           // B*T
    unsigned short* Xb  = (unsigned short*)d_ws;       // [16384][1024]
    unsigned short* Wqb = Xb + MT * 1024;              // [2][1024][1024] (Wq,Wk bf16)
    unsigned short* Wkb = Wqb + 1048576;
    unsigned short* Wvt = Wkb + 1048576;               // [1024 n][1024 c]
    unsigned short* Y   = Wvt + 1048576;               // [16384][1024]  (= X.Wqk)
    unsigned short* Z   = Y + MT * 1024;               // [1024][1024]   (= Wk.Wq^T)
    unsigned short* Vt  = Z + MT * 1024;               // [8][1024 v][2048 t]
    unsigned short* E   = Vt + 8L * 1024 * 2048;       // [8][2048 q][2048 t]
    float* colsum = (float*)(E + 8L * 2048 * 2048);    // [16384]
    float* u      = colsum + 16384;                    // [16384]
    float* v      = u + 16384;                         // [16384]
    float* cbuf   = v + 16384;
    float* wqbk   = cbuf + 1;                          // [1024]
    float* wkbq   = wqbk + 1024;                       // [1024]
    size_t need = (size_t)((char*)(wkbq + 1024) - (char*)d_ws);
    if (ws_size < need) return;

    // 0. zero colsum,u,v (contiguous)
    hipMemsetAsync(colsum, 0, 3L * 16384 * sizeof(float), stream);
    // 1. wqbk/wkbq/c
    wdots<<<257, 256, 0, stream>>>(Wq, bq, Wk, bk, wqbk, wkbq, cbuf);
    // 2. X -> bf16, fused u,v dots
    conv_x<<<8192, 256, 0, stream>>>(x, Xb, wqbk, wkbq, u, v);
    // 3. weights -> bf16 (Wq,Wk one dispatch) + Wv transpose
    conv_w2<<<dim3(512, 2), 256, 0, stream>>>(Wq, Wk, Wqb);
    transpose_wv<<<dim3(32, 32), 256, 0, stream>>>(Wv, Wvt);
    // 4. Z = Wk.Wq^T  (so Z[n][k] = Wqk[k][n] = scores B-operand form)
    gemm128<0><<<dim3(8, 8, 1), 256, 0, stream>>>(
        Wkb, Wqb, Z, 1024, 1024, 1024, 1024, 0, 0, 0, nullptr, nullptr);
    // 5. Y = X.Wqk  (A = Xb, Bt = Z)  -- replaces the Q projection
    gemm128<0><<<dim3(8, 128, 1), 256, 0, stream>>>(
        Xb, Z, Y, 16384, 1024, 1024, 1024, 0, 0, 0, nullptr, nullptr);
    // 6. E = exp((Y.X^T + u + v + c)/32) + atomic colsums  (K proj eliminated)
    gemm128<2><<<dim3(16, 16, 8), 256, 0, stream>>>(
        Y, Xb, E, 2048, 2048, 1024, 2048,
        2048L * 1024, 2048L * 1024, 2048L * 2048, u, colsum);
    // 7. Vt[b] = ((X_b Wv + bv)^T) / colsum  -- scale_vt fused into epilogue
    gemm128<1><<<dim3(16, 8, 8), 256, 0, stream>>>(
        Wvt, Xb, Vt, 1024, 2048, 1024, 2048,
        0, 2048L * 1024, 1024L * 2048, bv, colsum);
    // 8. out[b] = E_b @ Vn_b^T * mask
    gemm128<3><<<dim3(8, 16, 8), 256, 0, stream>>>(
        E, Vt, out, 2048, 1024, 2048, 1024,
        2048L * 2048, 1024L * 2048, 2048L * 1024, mask, nullptr);
}